// Round 6
// baseline (504.685 us; speedup 1.0000x reference)
//
#include <hip/hip_runtime.h>

#define NN 100000
#define NE 1600000
#define NBK 391                     // buckets of 256 dst nodes
#define CHUNK 8192
#define NBLK ((NE + CHUNK - 1) / CHUNK)   // 196
#define MPAD 100096                 // NN padded to multiple of 128
#define NCAST4 (NN * 32)            // float4 count for x cast
#define CASTB 12500                 // NCAST4 / 256
#define GBLK 2048                   // gather47 blocks
#define NPW ((NN + 8191) / 8192)    // nodes per wave = 13

using bf16x8 = __attribute__((ext_vector_type(8))) short;
using f32x4  = __attribute__((ext_vector_type(4))) float;

static __device__ __forceinline__ unsigned short f2bf(float f) {
    unsigned int u = __float_as_uint(f);
    unsigned int r = (u + 0x7FFFu + ((u >> 16) & 1u)) >> 16;   // RNE
    return (unsigned short)r;
}
static __device__ __forceinline__ float lo16(unsigned int u) {
    return __uint_as_float(u << 16);
}
static __device__ __forceinline__ float hi16(unsigned int u) {
    return __uint_as_float(u & 0xFFFF0000u);
}

// ================= CSR build =================

__global__ __launch_bounds__(256) void k_hist(const int* __restrict__ dst,
                                              int* __restrict__ ghist) {
    __shared__ int h[NBK];
    int b = blockIdx.x, t = threadIdx.x;
    for (int i = t; i < NBK; i += 256) h[i] = 0;
    __syncthreads();
    int beg = b * CHUNK, end = min(beg + CHUNK, NE);
    for (int i = beg + t; i < end; i += 256)
        atomicAdd(&h[dst[i] >> 8], 1);
    __syncthreads();
    for (int i = t; i < NBK; i += 256) ghist[b * NBK + i] = h[i];
}

__global__ __launch_bounds__(512) void k_basescan(const int* __restrict__ ghist,
                                                  int* __restrict__ boff,
                                                  int* __restrict__ gbase) {
    __shared__ int s[512];
    int t = threadIdx.x;
    int tot = 0;
    if (t < NBK)
        for (int blk = 0; blk < NBLK; ++blk) tot += ghist[blk * NBK + t];
    s[t] = tot;
    __syncthreads();
    for (int o = 1; o < 512; o <<= 1) {
        int u = (t >= o) ? s[t - o] : 0;
        __syncthreads();
        s[t] += u;
        __syncthreads();
    }
    int base = s[t] - tot;
    if (t <= NBK) boff[t] = base;
    if (t < NBK) {
        int run = base;
        for (int blk = 0; blk < NBLK; ++blk) {
            int g = ghist[blk * NBK + t];
            gbase[blk * NBK + t] = run;
            run += g;
        }
    }
}

__global__ __launch_bounds__(256) void k_scatter(const int* __restrict__ src,
                                                 const int* __restrict__ dst,
                                                 const int* __restrict__ gbase,
                                                 unsigned int* __restrict__ eb) {
    __shared__ int cur[NBK];
    int b = blockIdx.x, t = threadIdx.x;
    for (int i = t; i < NBK; i += 256) cur[i] = gbase[b * NBK + i];
    __syncthreads();
    int beg = b * CHUNK, end = min(beg + CHUNK, NE);
    for (int i = beg + t; i < end; i += 256) {
        int d = dst[i];
        int p = atomicAdd(&cur[d >> 8], 1);
        eb[p] = ((unsigned int)(d & 255) << 24) | (unsigned int)src[i];
    }
}

// fused: per-bucket degree hist -> LDS scan -> row_ptr -> col fill
__global__ __launch_bounds__(256) void k_csr(const unsigned int* __restrict__ eb,
                                             const int* __restrict__ boff,
                                             int* __restrict__ rp,
                                             int* __restrict__ col) {
    __shared__ int h[256];
    __shared__ int sc[256];
    __shared__ int cur[256];
    int b = blockIdx.x, t = threadIdx.x;
    h[t] = 0;
    __syncthreads();
    int beg = boff[b], end = boff[b + 1];
    for (int e = beg + t; e < end; e += 256)
        atomicAdd(&h[eb[e] >> 24], 1);
    __syncthreads();
    int c = h[t];
    sc[t] = c;
    __syncthreads();
    for (int o = 1; o < 256; o <<= 1) {
        int v = (t >= o) ? sc[t - o] : 0;
        __syncthreads();
        sc[t] += v;
        __syncthreads();
    }
    int excl = beg + sc[t] - c;
    int node = (b << 8) + t;
    if (node < NN) rp[node] = excl;
    if (node == NN - 1) rp[NN] = NE;
    cur[t] = excl;
    __syncthreads();
    for (int e = beg + t; e < end; e += 256) {
        unsigned int p = eb[e];
        int pos = atomicAdd(&cur[p >> 24], 1);
        col[pos] = (int)(p & 0xFFFFFFu);
    }
}

// ================= fused prep: cast x->bf16, build BT0/BT1/BT2 =================

__global__ __launch_bounds__(256) void k_prep(
        const float4* __restrict__ x4, ushort4* __restrict__ XB4,
        const float* __restrict__ Ws0, const float* __restrict__ Wn0,
        unsigned short* __restrict__ BT0,
        const float* __restrict__ Ws1, const float* __restrict__ Wn1,
        unsigned short* __restrict__ BT1,
        const float* __restrict__ Ws2, const float* __restrict__ Wn2,
        unsigned short* __restrict__ BT2) {
    int bid = blockIdx.x, t = threadIdx.x;
    if (bid < CASTB) {
        int i = bid * 256 + t;
        float4 v = x4[i];
        ushort4 o;
        o.x = f2bf(v.x); o.y = f2bf(v.y); o.z = f2bf(v.z); o.w = f2bf(v.w);
        XB4[i] = o;
    } else if (bid < CASTB + 128) {
        int idx = (bid - CASTB) * 256 + t;
        int k = idx >> 7, n = idx & 127;
        float v = (k < 128) ? Ws0[k * 128 + n] : Wn0[(k - 128) * 128 + n];
        BT0[n * 256 + k] = f2bf(v);
    } else if (bid < CASTB + 256) {
        int idx = (bid - CASTB - 128) * 256 + t;
        int k = idx >> 7, n = idx & 127;
        float v = (k < 128) ? Ws1[k * 128 + n] : Wn1[(k - 128) * 128 + n];
        BT1[n * 256 + k] = f2bf(v);
    } else {
        int idx = (bid - CASTB - 256) * 256 + t;
        if (idx < 96 * 128) {
            int n = idx >> 7, k = idx & 127;
            float v = 0.f;
            if (n < 48) { if (n < 47) v = Ws2[k * 47 + n]; }
            else        { int cc = n - 48; if (cc < 47) v = Wn2[k * 47 + cc]; }
            BT2[n * 128 + k] = f2bf(v);
        }
    }
}

// ===== fused layer: gather(mean of in-neighbors) -> LDS -> MFMA GEMM =====
// outB = bf16(relu([Ain | mean_gather(Ain)] @ BT^T + b)).  outB MUST NOT alias Ain.

__global__ __launch_bounds__(256, 2) void k_fused(
        const unsigned short* __restrict__ Ain,   // [MPAD][128] bf16
        const unsigned short* __restrict__ BT,    // [128][256] bf16
        const float* __restrict__ bias,
        const int* __restrict__ rp, const int* __restrict__ col,
        unsigned short* __restrict__ outB) {      // [MPAD][128] bf16
    __shared__ char hnl[128 * 256];   // 128 rows x 256B, XOR-swizzled bf16
    int t = threadIdx.x;
    int lane = t & 63, wid = t >> 6;
    int row0 = blockIdx.x * 128;
    int half = lane >> 5, l32 = lane & 31;
    const uint2* hb2 = (const uint2*)Ain;

    // ---- phase 1: each wave gathers 32 consecutive local rows ----
    for (int i = 0; i < 32; ++i) {
        int lrow = wid * 32 + i;
        int node = row0 + lrow;
        int beg = 0, end = 0;
        if (node < NN) { beg = rp[node]; end = rp[node + 1]; }
        float a0 = 0.f, a1 = 0.f, a2 = 0.f, a3 = 0.f;
        float b0 = 0.f, b1 = 0.f, b2 = 0.f, b3 = 0.f;
        for (int e = beg; e < end; e += 16) {
            // masked batch of 16 edges: 8 uint2 row-loads in flight
            int o0 = e + half,      o1 = e + 2 + half,  o2 = e + 4 + half,  o3 = e + 6 + half;
            int o4 = e + 8 + half,  o5 = e + 10 + half, o6 = e + 12 + half, o7 = e + 14 + half;
            bool p0 = o0 < end, p1 = o1 < end, p2 = o2 < end, p3 = o3 < end;
            bool p4 = o4 < end, p5 = o5 < end, p6 = o6 < end, p7 = o7 < end;
            uint2 z = make_uint2(0u, 0u);
            uint2 v0 = p0 ? hb2[(size_t)col[o0] * 32 + l32] : z;
            uint2 v1 = p1 ? hb2[(size_t)col[o1] * 32 + l32] : z;
            uint2 v2 = p2 ? hb2[(size_t)col[o2] * 32 + l32] : z;
            uint2 v3 = p3 ? hb2[(size_t)col[o3] * 32 + l32] : z;
            uint2 v4 = p4 ? hb2[(size_t)col[o4] * 32 + l32] : z;
            uint2 v5 = p5 ? hb2[(size_t)col[o5] * 32 + l32] : z;
            uint2 v6 = p6 ? hb2[(size_t)col[o6] * 32 + l32] : z;
            uint2 v7 = p7 ? hb2[(size_t)col[o7] * 32 + l32] : z;
            a0 += lo16(v0.x); a1 += hi16(v0.x); a2 += lo16(v0.y); a3 += hi16(v0.y);
            b0 += lo16(v1.x); b1 += hi16(v1.x); b2 += lo16(v1.y); b3 += hi16(v1.y);
            a0 += lo16(v2.x); a1 += hi16(v2.x); a2 += lo16(v2.y); a3 += hi16(v2.y);
            b0 += lo16(v3.x); b1 += hi16(v3.x); b2 += lo16(v3.y); b3 += hi16(v3.y);
            a0 += lo16(v4.x); a1 += hi16(v4.x); a2 += lo16(v4.y); a3 += hi16(v4.y);
            b0 += lo16(v5.x); b1 += hi16(v5.x); b2 += lo16(v5.y); b3 += hi16(v5.y);
            a0 += lo16(v6.x); a1 += hi16(v6.x); a2 += lo16(v6.y); a3 += hi16(v6.y);
            b0 += lo16(v7.x); b1 += hi16(v7.x); b2 += lo16(v7.y); b3 += hi16(v7.y);
        }
        float s0 = a0 + b0, s1 = a1 + b1, s2 = a2 + b2, s3 = a3 + b3;
        s0 += __shfl_xor(s0, 32);
        s1 += __shfl_xor(s1, 32);
        s2 += __shfl_xor(s2, 32);
        s3 += __shfl_xor(s3, 32);
        if (half == 0) {
            float d = (float)(end - beg);
            float inv = (d > 0.f) ? 1.0f / d : 0.0f;
            uint2 o;
            o.x = ((unsigned int)f2bf(s1 * inv) << 16) | (unsigned int)f2bf(s0 * inv);
            o.y = ((unsigned int)f2bf(s3 * inv) << 16) | (unsigned int)f2bf(s2 * inv);
            int bco = (l32 * 8) ^ ((lrow & 7) << 4);
            *(uint2*)&hnl[lrow * 256 + bco] = o;
        }
    }
    __syncthreads();

    // ---- phase 2: MFMA GEMM ----
    int wm = wid >> 1, wn = wid & 1;
    int lr = lane & 15, lg = lane >> 4;
    int rw0 = row0 + wm * 64;
    int colw = wn * 64;
    f32x4 zero = {0.f, 0.f, 0.f, 0.f};
    f32x4 acc[4][4];
#pragma unroll
    for (int a = 0; a < 4; ++a)
#pragma unroll
        for (int b = 0; b < 4; ++b) acc[a][b] = zero;

    // self part (p=0): A from global
    {
        bf16x8 bReg[4][4];
#pragma unroll
        for (int nf = 0; nf < 4; ++nf)
#pragma unroll
            for (int ks = 0; ks < 4; ++ks)
                bReg[nf][ks] = *(const bf16x8*)&BT[(size_t)(colw + nf * 16 + lr) * 256 + ks * 32 + lg * 8];
#pragma unroll
        for (int mf = 0; mf < 4; ++mf) {
            const unsigned short* Ar = Ain + (size_t)(rw0 + mf * 16 + lr) * 128;
            bf16x8 aReg[4];
#pragma unroll
            for (int ks = 0; ks < 4; ++ks)
                aReg[ks] = *(const bf16x8*)&Ar[ks * 32 + lg * 8];
#pragma unroll
            for (int ks = 0; ks < 4; ++ks)
#pragma unroll
                for (int nf = 0; nf < 4; ++nf)
                    acc[mf][nf] = __builtin_amdgcn_mfma_f32_16x16x32_bf16(
                        aReg[ks], bReg[nf][ks], acc[mf][nf], 0, 0, 0);
        }
    }
    // neighbor part (p=1): A from swizzled LDS
    {
        bf16x8 bReg[4][4];
#pragma unroll
        for (int nf = 0; nf < 4; ++nf)
#pragma unroll
            for (int ks = 0; ks < 4; ++ks)
                bReg[nf][ks] = *(const bf16x8*)&BT[(size_t)(colw + nf * 16 + lr) * 256 + 128 + ks * 32 + lg * 8];
#pragma unroll
        for (int mf = 0; mf < 4; ++mf) {
            int ar = wm * 64 + mf * 16 + lr;
            bf16x8 aReg[4];
#pragma unroll
            for (int ks = 0; ks < 4; ++ks) {
                int bco = (ks * 64 + lg * 16) ^ ((ar & 7) << 4);
                aReg[ks] = *(const bf16x8*)&hnl[ar * 256 + bco];
            }
#pragma unroll
            for (int ks = 0; ks < 4; ++ks)
#pragma unroll
                for (int nf = 0; nf < 4; ++nf)
                    acc[mf][nf] = __builtin_amdgcn_mfma_f32_16x16x32_bf16(
                        aReg[ks], bReg[nf][ks], acc[mf][nf], 0, 0, 0);
        }
    }
#pragma unroll
    for (int nf = 0; nf < 4; ++nf) {
        int cidx = colw + nf * 16 + lr;
        float bb = bias[cidx];
#pragma unroll
        for (int mf = 0; mf < 4; ++mf) {
#pragma unroll
            for (int j = 0; j < 4; ++j) {
                int row = rw0 + mf * 16 + lg * 4 + j;
                if (row < NN) {
                    float v = fmaxf(acc[mf][nf][j] + bb, 0.f);
                    outB[(size_t)row * 128 + cidx] = f2bf(v);
                }
            }
        }
    }
}

// ====== layer 2 MFMA: S = h2@Ws2+b2 (fp32), T = h2@Wn2 (bf16), BN=96 ======

__global__ __launch_bounds__(256, 2) void k_mgemm47(
        const unsigned short* __restrict__ A,
        const unsigned short* __restrict__ BT2,
        const float* __restrict__ bias,
        float* __restrict__ S,
        unsigned short* __restrict__ TB) {
    int t = threadIdx.x;
    int lane = t & 63, wid = t >> 6;
    int wm = wid >> 1, wn = wid & 1;
    int lr = lane & 15, lg = lane >> 4;
    int row0 = blockIdx.x * 128 + wm * 64;
    int colw = wn * 48;
    f32x4 zero = {0.f, 0.f, 0.f, 0.f};
    f32x4 acc[4][3];
#pragma unroll
    for (int a = 0; a < 4; ++a)
#pragma unroll
        for (int b = 0; b < 3; ++b) acc[a][b] = zero;

    bf16x8 bReg[3][4];
#pragma unroll
    for (int nf = 0; nf < 3; ++nf)
#pragma unroll
        for (int ks = 0; ks < 4; ++ks)
            bReg[nf][ks] = *(const bf16x8*)&BT2[(size_t)(colw + nf * 16 + lr) * 128 + ks * 32 + lg * 8];
#pragma unroll
    for (int mf = 0; mf < 4; ++mf) {
        const unsigned short* Ar = A + (size_t)(row0 + mf * 16 + lr) * 128;
        bf16x8 aReg[4];
#pragma unroll
        for (int ks = 0; ks < 4; ++ks)
            aReg[ks] = *(const bf16x8*)&Ar[ks * 32 + lg * 8];
#pragma unroll
        for (int ks = 0; ks < 4; ++ks)
#pragma unroll
            for (int nf = 0; nf < 3; ++nf)
                acc[mf][nf] = __builtin_amdgcn_mfma_f32_16x16x32_bf16(
                    aReg[ks], bReg[nf][ks], acc[mf][nf], 0, 0, 0);
    }
#pragma unroll
    for (int nf = 0; nf < 3; ++nf) {
        int cidx = colw + nf * 16 + lr;      // 0..95
#pragma unroll
        for (int mf = 0; mf < 4; ++mf) {
#pragma unroll
            for (int j = 0; j < 4; ++j) {
                int row = row0 + mf * 16 + lg * 4 + j;
                if (row < NN) {
                    float v = acc[mf][nf][j];
                    if (cidx < 47)
                        S[(size_t)row * 48 + cidx] = v + bias[cidx];
                    else if (cidx >= 48)
                        TB[(size_t)row * 48 + (cidx - 48)] = f2bf(v);
                }
            }
        }
    }
}

// ======== layer-2 aggregate: out = S + mean(TB), grid-strided, 2 edges/load ========

__global__ __launch_bounds__(256) void k_gather47(
        const unsigned int* __restrict__ TB32,   // [node][24] uint (96B bf16 rows)
        const float2* __restrict__ S2,           // [node][24] float2
        const int* __restrict__ rp, const int* __restrict__ col,
        float* __restrict__ out) {
    int wave = blockIdx.x * 4 + (threadIdx.x >> 6);
    int lane = threadIdx.x & 63;
    int half = lane >> 5, l32 = lane & 31;
    bool act = l32 < 24;
    int n0 = wave * NPW;
    int n1 = min(n0 + NPW, NN);
    for (int node = n0; node < n1; ++node) {
        int beg = rp[node], end = rp[node + 1];
        float c0a = 0.f, c1a = 0.f, c0b = 0.f, c1b = 0.f;
        int e = beg;
        for (; e + 8 <= end; e += 8) {
            int i0 = col[e + half];
            int i1 = col[e + 2 + half];
            int i2 = col[e + 4 + half];
            int i3 = col[e + 6 + half];
            if (act) {
                unsigned int u0 = TB32[(size_t)i0 * 24 + l32];
                unsigned int u1 = TB32[(size_t)i1 * 24 + l32];
                unsigned int u2 = TB32[(size_t)i2 * 24 + l32];
                unsigned int u3 = TB32[(size_t)i3 * 24 + l32];
                c0a += lo16(u0); c1a += hi16(u0);
                c0b += lo16(u1); c1b += hi16(u1);
                c0a += lo16(u2); c1a += hi16(u2);
                c0b += lo16(u3); c1b += hi16(u3);
            }
        }
        for (; e < end; e += 2) {
            if (act && e + half < end) {
                unsigned int u = TB32[(size_t)col[e + half] * 24 + l32];
                c0a += lo16(u); c1a += hi16(u);
            }
        }
        float s0 = c0a + c0b, s1 = c1a + c1b;
        s0 += __shfl_xor(s0, 32);
        s1 += __shfl_xor(s1, 32);
        if (half == 0 && act) {
            float d = (float)(end - beg);
            float inv = (d > 0.f) ? 1.0f / d : 0.0f;
            float2 sv = S2[(size_t)node * 24 + l32];
            int c = l32 * 2;
            out[(size_t)node * 47 + c] = sv.x + s0 * inv;
            if (c + 1 < 47) out[(size_t)node * 47 + c + 1] = sv.y + s1 * inv;
        }
    }
}

// ================= launcher =================

static inline size_t align_up(size_t x, size_t a) { return (x + a - 1) / a * a; }

extern "C" void kernel_launch(void* const* d_in, const int* in_sizes, int n_in,
                              void* d_out, int out_size, void* d_ws, size_t ws_size,
                              hipStream_t stream) {
    const float* x   = (const float*)d_in[0];
    const int* src   = (const int*)d_in[1];
    const int* dst   = (const int*)d_in[2];
    const float* Ws0 = (const float*)d_in[3];
    const float* Wn0 = (const float*)d_in[4];
    const float* b0  = (const float*)d_in[5];
    const float* Ws1 = (const float*)d_in[6];
    const float* Wn1 = (const float*)d_in[7];
    const float* b1  = (const float*)d_in[8];
    const float* Ws2 = (const float*)d_in[9];
    const float* Wn2 = (const float*)d_in[10];
    const float* b2  = (const float*)d_in[11];
    float* out = (float*)d_out;

    char* ws = (char*)d_ws;
    size_t off = 0;
    auto alloc = [&](size_t bytes) -> void* {
        void* p = ws + off; off = align_up(off + bytes, 256); return p;
    };
    int* row_ptr = (int*)alloc((size_t)(NN + 1) * 4);
    int* boff    = (int*)alloc((size_t)(NBK + 1) * 4);
    int* gbase   = (int*)alloc((size_t)NBLK * NBK * 4);
    int* ghist   = (int*)alloc((size_t)NBLK * NBK * 4);
    int* col     = (int*)alloc((size_t)NE * 4);
    unsigned short* XB0 = (unsigned short*)alloc((size_t)MPAD * 128 * 2);  // 25.6MB
    unsigned short* XB1 = (unsigned short*)alloc((size_t)MPAD * 128 * 2);  // 25.6MB
    unsigned short* BT0 = (unsigned short*)alloc(128 * 256 * 2);
    unsigned short* BT1 = (unsigned short*)alloc(128 * 256 * 2);
    unsigned short* BT2 = (unsigned short*)alloc(96 * 128 * 2);
    char* big = (char*)alloc((size_t)NN * 48 * 4 + (size_t)NN * 48 * 2);   // S + TB
    unsigned int* eb    = (unsigned int*)XB1;   // alias: eb dead before XB1 written
    float* S            = (float*)big;
    unsigned short* TB  = (unsigned short*)(big + (size_t)NN * 48 * 4);

    // --- CSR build (no global atomics) ---
    k_hist<<<NBLK, 256, 0, stream>>>(dst, ghist);
    k_basescan<<<1, 512, 0, stream>>>(ghist, boff, gbase);
    k_scatter<<<NBLK, 256, 0, stream>>>(src, dst, gbase, eb);
    k_csr<<<NBK, 256, 0, stream>>>(eb, boff, row_ptr, col);

    // --- fused prep: cast + all weight transposes ---
    k_prep<<<CASTB + 256 + 48, 256, 0, stream>>>(
        (const float4*)x, (ushort4*)XB0, Ws0, Wn0, BT0, Ws1, Wn1, BT1, Ws2, Wn2, BT2);

    int mgrid = MPAD / 128;   // 782

    // --- layer 0: XB0 -> XB1 ---
    k_fused<<<mgrid, 256, 0, stream>>>(XB0, BT0, b0, row_ptr, col, XB1);
    // --- layer 1: XB1 -> XB0 ---
    k_fused<<<mgrid, 256, 0, stream>>>(XB1, BT1, b1, row_ptr, col, XB0);
    // --- layer 2 ---
    k_mgemm47<<<mgrid, 256, 0, stream>>>(XB0, BT2, b2, S, TB);
    k_gather47<<<GBLK, 256, 0, stream>>>((const unsigned int*)TB, (const float2*)S,
                                         row_ptr, col, out);
}

// Round 7
// 421.153 us; speedup vs baseline: 1.1983x; 1.1983x over previous
//
#include <hip/hip_runtime.h>

#define NN 100000
#define NE 1600000
#define NBK 391                     // buckets of 256 dst nodes
#define CHUNK 8192
#define NBLK ((NE + CHUNK - 1) / CHUNK)   // 196
#define MPAD 100096                 // NN padded to multiple of 128
#define NCAST4 (NN * 32)            // float4 count for x cast
#define CAST512 (NCAST4 / 512)      // 6250
#define GBLK 2048                   // gather blocks (8192 waves)
#define NPW ((NN + 8191) / 8192)    // nodes per wave = 13

using bf16x8 = __attribute__((ext_vector_type(8))) short;
using f32x4  = __attribute__((ext_vector_type(4))) float;

static __device__ __forceinline__ unsigned short f2bf(float f) {
    unsigned int u = __float_as_uint(f);
    unsigned int r = (u + 0x7FFFu + ((u >> 16) & 1u)) >> 16;   // RNE
    return (unsigned short)r;
}
static __device__ __forceinline__ float lo16(unsigned int u) {
    return __uint_as_float(u << 16);
}
static __device__ __forceinline__ float hi16(unsigned int u) {
    return __uint_as_float(u & 0xFFFF0000u);
}

// ================= CSR build =================

__global__ __launch_bounds__(256) void k_hist(const int* __restrict__ dst,
                                              int* __restrict__ ghist) {
    __shared__ int h[NBK];
    int b = blockIdx.x, t = threadIdx.x;
    for (int i = t; i < NBK; i += 256) h[i] = 0;
    __syncthreads();
    int beg = b * CHUNK, end = min(beg + CHUNK, NE);
    for (int i = beg + t; i < end; i += 256)
        atomicAdd(&h[dst[i] >> 8], 1);
    __syncthreads();
    for (int i = t; i < NBK; i += 256) ghist[b * NBK + i] = h[i];
}

// block 0: bucket scan -> boff + per-(block,bucket) bases; blocks 1..: prep work
__global__ __launch_bounds__(512) void k_basescan_prep(
        const int* __restrict__ ghist, int* __restrict__ boff, int* __restrict__ gbase,
        const float4* __restrict__ x4, ushort4* __restrict__ XB4,
        const float* __restrict__ Ws0, const float* __restrict__ Wn0,
        unsigned short* __restrict__ BT0,
        const float* __restrict__ Ws1, const float* __restrict__ Wn1,
        unsigned short* __restrict__ BT1,
        const float* __restrict__ Ws2, const float* __restrict__ Wn2,
        unsigned short* __restrict__ BT2) {
    __shared__ int s[512];
    int bid = blockIdx.x, t = threadIdx.x;
    if (bid == 0) {
        int tot = 0;
        if (t < NBK) {
#pragma unroll 4
            for (int blk = 0; blk < NBLK; ++blk) tot += ghist[blk * NBK + t];
        }
        s[t] = tot;
        __syncthreads();
        for (int o = 1; o < 512; o <<= 1) {
            int u = (t >= o) ? s[t - o] : 0;
            __syncthreads();
            s[t] += u;
            __syncthreads();
        }
        int base = s[t] - tot;
        if (t <= NBK) boff[t] = base;
        if (t < NBK) {
            int run = base;
            for (int blk = 0; blk < NBLK; ++blk) {
                int g = ghist[blk * NBK + t];
                gbase[blk * NBK + t] = run;
                run += g;
            }
        }
        return;
    }
    int pb = bid - 1;
    if (pb < CAST512) {
        int i = pb * 512 + t;
        float4 v = x4[i];
        ushort4 o;
        o.x = f2bf(v.x); o.y = f2bf(v.y); o.z = f2bf(v.z); o.w = f2bf(v.w);
        XB4[i] = o;
    } else if (pb < CAST512 + 64) {
        int idx = (pb - CAST512) * 512 + t;
        int k = idx >> 7, n = idx & 127;
        float v = (k < 128) ? Ws0[k * 128 + n] : Wn0[(k - 128) * 128 + n];
        BT0[n * 256 + k] = f2bf(v);
    } else if (pb < CAST512 + 128) {
        int idx = (pb - CAST512 - 64) * 512 + t;
        int k = idx >> 7, n = idx & 127;
        float v = (k < 128) ? Ws1[k * 128 + n] : Wn1[(k - 128) * 128 + n];
        BT1[n * 256 + k] = f2bf(v);
    } else {
        int idx = (pb - CAST512 - 128) * 512 + t;
        if (idx < 96 * 128) {
            int n = idx >> 7, k = idx & 127;
            float v = 0.f;
            if (n < 48) { if (n < 47) v = Ws2[k * 47 + n]; }
            else        { int cc = n - 48; if (cc < 47) v = Wn2[k * 47 + cc]; }
            BT2[n * 128 + k] = f2bf(v);
        }
    }
}

__global__ __launch_bounds__(256) void k_scatter(const int* __restrict__ src,
                                                 const int* __restrict__ dst,
                                                 const int* __restrict__ gbase,
                                                 unsigned int* __restrict__ eb) {
    __shared__ int cur[NBK];
    int b = blockIdx.x, t = threadIdx.x;
    for (int i = t; i < NBK; i += 256) cur[i] = gbase[b * NBK + i];
    __syncthreads();
    int beg = b * CHUNK, end = min(beg + CHUNK, NE);
    for (int i = beg + t; i < end; i += 256) {
        int d = dst[i];
        int p = atomicAdd(&cur[d >> 8], 1);
        eb[p] = ((unsigned int)(d & 255) << 24) | (unsigned int)src[i];
    }
}

// fused: per-bucket degree hist -> LDS scan -> row_ptr -> col fill
__global__ __launch_bounds__(256) void k_csr(const unsigned int* __restrict__ eb,
                                             const int* __restrict__ boff,
                                             int* __restrict__ rp,
                                             int* __restrict__ col) {
    __shared__ int h[256];
    __shared__ int sc[256];
    __shared__ int cur[256];
    int b = blockIdx.x, t = threadIdx.x;
    h[t] = 0;
    __syncthreads();
    int beg = boff[b], end = boff[b + 1];
    for (int e = beg + t; e < end; e += 256)
        atomicAdd(&h[eb[e] >> 24], 1);
    __syncthreads();
    int c = h[t];
    sc[t] = c;
    __syncthreads();
    for (int o = 1; o < 256; o <<= 1) {
        int v = (t >= o) ? sc[t - o] : 0;
        __syncthreads();
        sc[t] += v;
        __syncthreads();
    }
    int excl = beg + sc[t] - c;
    int node = (b << 8) + t;
    if (node < NN) rp[node] = excl;
    if (node == NN - 1) rp[NN] = NE;
    cur[t] = excl;
    __syncthreads();
    for (int e = beg + t; e < end; e += 256) {
        unsigned int p = eb[e];
        int pos = atomicAdd(&cur[p >> 24], 1);
        col[pos] = (int)(p & 0xFFFFFFu);
    }
}

// ======== mean-aggregate gather 128-feat: grid-strided, masked 16-edge batches ========

__global__ __launch_bounds__(256) void k_gather128(
        const uint2* __restrict__ hb2,   // [node][32] uint2 (256B bf16 rows)
        const int* __restrict__ rp, const int* __restrict__ col,
        uint2* __restrict__ hnb2) {
    int wave = blockIdx.x * 4 + (threadIdx.x >> 6);
    int lane = threadIdx.x & 63;
    int half = lane >> 5, l32 = lane & 31;
    int n0 = wave * NPW;
    int n1 = min(n0 + NPW, NN);
    for (int node = n0; node < n1; ++node) {
        int beg = rp[node], end = rp[node + 1];
        float a0 = 0.f, a1 = 0.f, a2 = 0.f, a3 = 0.f;
        float b0 = 0.f, b1 = 0.f, b2 = 0.f, b3 = 0.f;
        for (int e = beg; e < end; e += 16) {
            int o0 = e + half,      o1 = e + 2 + half,  o2 = e + 4 + half,  o3 = e + 6 + half;
            int o4 = e + 8 + half,  o5 = e + 10 + half, o6 = e + 12 + half, o7 = e + 14 + half;
            uint2 z = make_uint2(0u, 0u);
            uint2 v0 = (o0 < end) ? hb2[(size_t)col[o0] * 32 + l32] : z;
            uint2 v1 = (o1 < end) ? hb2[(size_t)col[o1] * 32 + l32] : z;
            uint2 v2 = (o2 < end) ? hb2[(size_t)col[o2] * 32 + l32] : z;
            uint2 v3 = (o3 < end) ? hb2[(size_t)col[o3] * 32 + l32] : z;
            uint2 v4 = (o4 < end) ? hb2[(size_t)col[o4] * 32 + l32] : z;
            uint2 v5 = (o5 < end) ? hb2[(size_t)col[o5] * 32 + l32] : z;
            uint2 v6 = (o6 < end) ? hb2[(size_t)col[o6] * 32 + l32] : z;
            uint2 v7 = (o7 < end) ? hb2[(size_t)col[o7] * 32 + l32] : z;
            a0 += lo16(v0.x); a1 += hi16(v0.x); a2 += lo16(v0.y); a3 += hi16(v0.y);
            b0 += lo16(v1.x); b1 += hi16(v1.x); b2 += lo16(v1.y); b3 += hi16(v1.y);
            a0 += lo16(v2.x); a1 += hi16(v2.x); a2 += lo16(v2.y); a3 += hi16(v2.y);
            b0 += lo16(v3.x); b1 += hi16(v3.x); b2 += lo16(v3.y); b3 += hi16(v3.y);
            a0 += lo16(v4.x); a1 += hi16(v4.x); a2 += lo16(v4.y); a3 += hi16(v4.y);
            b0 += lo16(v5.x); b1 += hi16(v5.x); b2 += lo16(v5.y); b3 += hi16(v5.y);
            a0 += lo16(v6.x); a1 += hi16(v6.x); a2 += lo16(v6.y); a3 += hi16(v6.y);
            b0 += lo16(v7.x); b1 += hi16(v7.x); b2 += lo16(v7.y); b3 += hi16(v7.y);
        }
        float s0 = a0 + b0, s1 = a1 + b1, s2 = a2 + b2, s3 = a3 + b3;
        s0 += __shfl_xor(s0, 32);
        s1 += __shfl_xor(s1, 32);
        s2 += __shfl_xor(s2, 32);
        s3 += __shfl_xor(s3, 32);
        if (half == 0) {
            float d = (float)(end - beg);
            float inv = (d > 0.f) ? 1.0f / d : 0.0f;
            uint2 o;
            o.x = ((unsigned int)f2bf(s1 * inv) << 16) | (unsigned int)f2bf(s0 * inv);
            o.y = ((unsigned int)f2bf(s3 * inv) << 16) | (unsigned int)f2bf(s2 * inv);
            hnb2[(size_t)node * 32 + l32] = o;
        }
    }
}

// ================= MFMA GEMM: outB = bf16(relu([A0|A1] @ BT^T + b)) =================

__global__ __launch_bounds__(256, 2) void k_mgemm(
        const unsigned short* __restrict__ A0,
        const unsigned short* __restrict__ A1,
        const unsigned short* __restrict__ BT,
        const float* __restrict__ bias,
        unsigned short* __restrict__ outB) {
    int t = threadIdx.x;
    int lane = t & 63, wid = t >> 6;
    int wm = wid >> 1, wn = wid & 1;
    int lr = lane & 15, lg = lane >> 4;
    int row0 = blockIdx.x * 128 + wm * 64;
    int colw = wn * 64;
    f32x4 zero = {0.f, 0.f, 0.f, 0.f};
    f32x4 acc[4][4];
#pragma unroll
    for (int a = 0; a < 4; ++a)
#pragma unroll
        for (int b = 0; b < 4; ++b) acc[a][b] = zero;

#pragma unroll
    for (int p = 0; p < 2; ++p) {
        const unsigned short* A = p ? A1 : A0;
        bf16x8 bReg[4][4];
#pragma unroll
        for (int nf = 0; nf < 4; ++nf)
#pragma unroll
            for (int ks = 0; ks < 4; ++ks)
                bReg[nf][ks] = *(const bf16x8*)&BT[(size_t)(colw + nf * 16 + lr) * 256 + p * 128 + ks * 32 + lg * 8];
#pragma unroll
        for (int mf = 0; mf < 4; ++mf) {
            const unsigned short* Ar = A + (size_t)(row0 + mf * 16 + lr) * 128;
            bf16x8 aReg[4];
#pragma unroll
            for (int ks = 0; ks < 4; ++ks)
                aReg[ks] = *(const bf16x8*)&Ar[ks * 32 + lg * 8];
#pragma unroll
            for (int ks = 0; ks < 4; ++ks)
#pragma unroll
                for (int nf = 0; nf < 4; ++nf)
                    acc[mf][nf] = __builtin_amdgcn_mfma_f32_16x16x32_bf16(
                        aReg[ks], bReg[nf][ks], acc[mf][nf], 0, 0, 0);
        }
    }
    __syncthreads();   // A0 aliases outB (in-place): drain all reads first
#pragma unroll
    for (int nf = 0; nf < 4; ++nf) {
        int cidx = colw + nf * 16 + lr;
        float bb = bias[cidx];
#pragma unroll
        for (int mf = 0; mf < 4; ++mf) {
#pragma unroll
            for (int j = 0; j < 4; ++j) {
                int row = row0 + mf * 16 + lg * 4 + j;
                if (row < NN) {
                    float v = fmaxf(acc[mf][nf][j] + bb, 0.f);
                    outB[(size_t)row * 128 + cidx] = f2bf(v);
                }
            }
        }
    }
}

// ====== layer 2 MFMA: S = h2@Ws2+b2 (fp32), T = h2@Wn2 (bf16), BN=96 ======

__global__ __launch_bounds__(256, 2) void k_mgemm47(
        const unsigned short* __restrict__ A,
        const unsigned short* __restrict__ BT2,
        const float* __restrict__ bias,
        float* __restrict__ S,
        unsigned short* __restrict__ TB) {
    int t = threadIdx.x;
    int lane = t & 63, wid = t >> 6;
    int wm = wid >> 1, wn = wid & 1;
    int lr = lane & 15, lg = lane >> 4;
    int row0 = blockIdx.x * 128 + wm * 64;
    int colw = wn * 48;
    f32x4 zero = {0.f, 0.f, 0.f, 0.f};
    f32x4 acc[4][3];
#pragma unroll
    for (int a = 0; a < 4; ++a)
#pragma unroll
        for (int b = 0; b < 3; ++b) acc[a][b] = zero;

    bf16x8 bReg[3][4];
#pragma unroll
    for (int nf = 0; nf < 3; ++nf)
#pragma unroll
        for (int ks = 0; ks < 4; ++ks)
            bReg[nf][ks] = *(const bf16x8*)&BT2[(size_t)(colw + nf * 16 + lr) * 128 + ks * 32 + lg * 8];
#pragma unroll
    for (int mf = 0; mf < 4; ++mf) {
        const unsigned short* Ar = A + (size_t)(row0 + mf * 16 + lr) * 128;
        bf16x8 aReg[4];
#pragma unroll
        for (int ks = 0; ks < 4; ++ks)
            aReg[ks] = *(const bf16x8*)&Ar[ks * 32 + lg * 8];
#pragma unroll
        for (int ks = 0; ks < 4; ++ks)
#pragma unroll
            for (int nf = 0; nf < 3; ++nf)
                acc[mf][nf] = __builtin_amdgcn_mfma_f32_16x16x32_bf16(
                    aReg[ks], bReg[nf][ks], acc[mf][nf], 0, 0, 0);
    }
#pragma unroll
    for (int nf = 0; nf < 3; ++nf) {
        int cidx = colw + nf * 16 + lr;      // 0..95
#pragma unroll
        for (int mf = 0; mf < 4; ++mf) {
#pragma unroll
            for (int j = 0; j < 4; ++j) {
                int row = row0 + mf * 16 + lg * 4 + j;
                if (row < NN) {
                    float v = acc[mf][nf][j];
                    if (cidx < 47)
                        S[(size_t)row * 48 + cidx] = v + bias[cidx];
                    else if (cidx >= 48)
                        TB[(size_t)row * 48 + (cidx - 48)] = f2bf(v);
                }
            }
        }
    }
}

// ======== layer-2 aggregate: out = S + mean(TB), masked 16-edge batches ========

__global__ __launch_bounds__(256) void k_gather47(
        const unsigned int* __restrict__ TB32,   // [node][24] uint (96B bf16 rows)
        const float2* __restrict__ S2,           // [node][24] float2
        const int* __restrict__ rp, const int* __restrict__ col,
        float* __restrict__ out) {
    int wave = blockIdx.x * 4 + (threadIdx.x >> 6);
    int lane = threadIdx.x & 63;
    int half = lane >> 5, l32 = lane & 31;
    bool act = l32 < 24;
    int n0 = wave * NPW;
    int n1 = min(n0 + NPW, NN);
    for (int node = n0; node < n1; ++node) {
        int beg = rp[node], end = rp[node + 1];
        float c0a = 0.f, c1a = 0.f, c0b = 0.f, c1b = 0.f;
        for (int e = beg; e < end; e += 16) {
            int o0 = e + half,      o1 = e + 2 + half,  o2 = e + 4 + half,  o3 = e + 6 + half;
            int o4 = e + 8 + half,  o5 = e + 10 + half, o6 = e + 12 + half, o7 = e + 14 + half;
            unsigned int u0 = (act && o0 < end) ? TB32[(size_t)col[o0] * 24 + l32] : 0u;
            unsigned int u1 = (act && o1 < end) ? TB32[(size_t)col[o1] * 24 + l32] : 0u;
            unsigned int u2 = (act && o2 < end) ? TB32[(size_t)col[o2] * 24 + l32] : 0u;
            unsigned int u3 = (act && o3 < end) ? TB32[(size_t)col[o3] * 24 + l32] : 0u;
            unsigned int u4 = (act && o4 < end) ? TB32[(size_t)col[o4] * 24 + l32] : 0u;
            unsigned int u5 = (act && o5 < end) ? TB32[(size_t)col[o5] * 24 + l32] : 0u;
            unsigned int u6 = (act && o6 < end) ? TB32[(size_t)col[o6] * 24 + l32] : 0u;
            unsigned int u7 = (act && o7 < end) ? TB32[(size_t)col[o7] * 24 + l32] : 0u;
            c0a += lo16(u0); c1a += hi16(u0);
            c0b += lo16(u1); c1b += hi16(u1);
            c0a += lo16(u2); c1a += hi16(u2);
            c0b += lo16(u3); c1b += hi16(u3);
            c0a += lo16(u4); c1a += hi16(u4);
            c0b += lo16(u5); c1b += hi16(u5);
            c0a += lo16(u6); c1a += hi16(u6);
            c0b += lo16(u7); c1b += hi16(u7);
        }
        float s0 = c0a + c0b, s1 = c1a + c1b;
        s0 += __shfl_xor(s0, 32);
        s1 += __shfl_xor(s1, 32);
        if (half == 0 && act) {
            float d = (float)(end - beg);
            float inv = (d > 0.f) ? 1.0f / d : 0.0f;
            float2 sv = S2[(size_t)node * 24 + l32];
            int c = l32 * 2;
            out[(size_t)node * 47 + c] = sv.x + s0 * inv;
            if (c + 1 < 47) out[(size_t)node * 47 + c + 1] = sv.y + s1 * inv;
        }
    }
}

// ================= launcher =================

static inline size_t align_up(size_t x, size_t a) { return (x + a - 1) / a * a; }

extern "C" void kernel_launch(void* const* d_in, const int* in_sizes, int n_in,
                              void* d_out, int out_size, void* d_ws, size_t ws_size,
                              hipStream_t stream) {
    const float* x   = (const float*)d_in[0];
    const int* src   = (const int*)d_in[1];
    const int* dst   = (const int*)d_in[2];
    const float* Ws0 = (const float*)d_in[3];
    const float* Wn0 = (const float*)d_in[4];
    const float* b0  = (const float*)d_in[5];
    const float* Ws1 = (const float*)d_in[6];
    const float* Wn1 = (const float*)d_in[7];
    const float* b1  = (const float*)d_in[8];
    const float* Ws2 = (const float*)d_in[9];
    const float* Wn2 = (const float*)d_in[10];
    const float* b2  = (const float*)d_in[11];
    float* out = (float*)d_out;

    char* ws = (char*)d_ws;
    size_t off = 0;
    auto alloc = [&](size_t bytes) -> void* {
        void* p = ws + off; off = align_up(off + bytes, 256); return p;
    };
    int* row_ptr = (int*)alloc((size_t)(NN + 1) * 4);
    int* boff    = (int*)alloc((size_t)(NBK + 1) * 4);
    int* gbase   = (int*)alloc((size_t)NBLK * NBK * 4);
    int* ghist   = (int*)alloc((size_t)NBLK * NBK * 4);
    int* col     = (int*)alloc((size_t)NE * 4);
    unsigned short* XB  = (unsigned short*)alloc((size_t)MPAD * 128 * 2);
    unsigned short* BT0 = (unsigned short*)alloc(128 * 256 * 2);
    unsigned short* BT1 = (unsigned short*)alloc(128 * 256 * 2);
    unsigned short* BT2 = (unsigned short*)alloc(96 * 128 * 2);
    char* big = (char*)alloc((size_t)NN * 48 * 4 * 2);   // 38.4MB, time-shared
    unsigned int* eb    = (unsigned int*)big;            // CSR build
    unsigned int* HNB   = (unsigned int*)big;            // gathered bf16 rows
    float* S            = (float*)big;
    unsigned short* TB  = (unsigned short*)(big + (size_t)NN * 48 * 4);

    // --- CSR build (no global atomics); prep fused into the scan launch ---
    k_hist<<<NBLK, 256, 0, stream>>>(dst, ghist);
    k_basescan_prep<<<1 + CAST512 + 128 + 24, 512, 0, stream>>>(
        ghist, boff, gbase,
        (const float4*)x, (ushort4*)XB, Ws0, Wn0, BT0, Ws1, Wn1, BT1, Ws2, Wn2, BT2);
    k_scatter<<<NBLK, 256, 0, stream>>>(src, dst, gbase, eb);
    k_csr<<<NBK, 256, 0, stream>>>(eb, boff, row_ptr, col);

    int mgrid = MPAD / 128;

    // --- layer 0 (bf16 in-place over XB) ---
    k_gather128<<<GBLK, 256, 0, stream>>>((const uint2*)XB, row_ptr, col, (uint2*)HNB);
    k_mgemm<<<mgrid, 256, 0, stream>>>(XB, (const unsigned short*)HNB, BT0, b0, XB);
    // --- layer 1 (bf16 in-place over XB) ---
    k_gather128<<<GBLK, 256, 0, stream>>>((const uint2*)XB, row_ptr, col, (uint2*)HNB);
    k_mgemm<<<mgrid, 256, 0, stream>>>(XB, (const unsigned short*)HNB, BT1, b1, XB);
    // --- layer 2 ---
    k_mgemm47<<<mgrid, 256, 0, stream>>>(XB, BT2, b2, S, TB);
    k_gather47<<<GBLK, 256, 0, stream>>>((const unsigned int*)TB, (const float2*)S,
                                         row_ptr, col, out);
}

// Round 8
// 367.163 us; speedup vs baseline: 1.3746x; 1.1470x over previous
//
#include <hip/hip_runtime.h>

#define NN 100000
#define NE 1600000
#define NBK 391                     // buckets of 256 dst nodes
#define CHUNK 8192
#define NBLK ((NE + CHUNK - 1) / CHUNK)   // 196
#define MPAD 100096                 // NN padded to multiple of 128
#define NCAST4 (NN * 32)            // float4 count for x cast
#define CAST512 (NCAST4 / 512)      // 6250
#define GBLK 2048                   // gather blocks (8192 waves)
#define NPW ((NN + 8191) / 8192)    // nodes per wave = 13

using bf16x8 = __attribute__((ext_vector_type(8))) short;
using f32x4  = __attribute__((ext_vector_type(4))) float;

static __device__ __forceinline__ unsigned short f2bf(float f) {
    unsigned int u = __float_as_uint(f);
    unsigned int r = (u + 0x7FFFu + ((u >> 16) & 1u)) >> 16;   // RNE
    return (unsigned short)r;
}
static __device__ __forceinline__ float lo16(unsigned int u) {
    return __uint_as_float(u << 16);
}
static __device__ __forceinline__ float hi16(unsigned int u) {
    return __uint_as_float(u & 0xFFFF0000u);
}

// ================= CSR build =================

__global__ __launch_bounds__(256) void k_hist(const int* __restrict__ dst,
                                              int* __restrict__ ghist) {
    __shared__ int h[NBK];
    int b = blockIdx.x, t = threadIdx.x;
    for (int i = t; i < NBK; i += 256) h[i] = 0;
    __syncthreads();
    int beg = b * CHUNK, end = min(beg + CHUNK, NE);
    for (int i = beg + t; i < end; i += 256)
        atomicAdd(&h[dst[i] >> 8], 1);
    __syncthreads();
    for (int i = t; i < NBK; i += 256) ghist[b * NBK + i] = h[i];
}

// block 0: bucket scan -> boff + per-(block,bucket) bases; blocks 1..: prep work
__global__ __launch_bounds__(512) void k_basescan_prep(
        const int* __restrict__ ghist, int* __restrict__ boff, int* __restrict__ gbase,
        const float4* __restrict__ x4, ushort4* __restrict__ XB4,
        const float* __restrict__ Ws0, const float* __restrict__ Wn0,
        unsigned short* __restrict__ BT0,
        const float* __restrict__ Ws1, const float* __restrict__ Wn1,
        unsigned short* __restrict__ BT1,
        const float* __restrict__ Ws2, const float* __restrict__ Wn2,
        unsigned short* __restrict__ BT2) {
    __shared__ int s[512];
    int bid = blockIdx.x, t = threadIdx.x;
    if (bid == 0) {
        int tot = 0;
        if (t < NBK) {
#pragma unroll 4
            for (int blk = 0; blk < NBLK; ++blk) tot += ghist[blk * NBK + t];
        }
        s[t] = tot;
        __syncthreads();
        for (int o = 1; o < 512; o <<= 1) {
            int u = (t >= o) ? s[t - o] : 0;
            __syncthreads();
            s[t] += u;
            __syncthreads();
        }
        int base = s[t] - tot;
        if (t <= NBK) boff[t] = base;
        if (t < NBK) {
            int run = base;
            for (int blk = 0; blk < NBLK; ++blk) {
                int g = ghist[blk * NBK + t];
                gbase[blk * NBK + t] = run;
                run += g;
            }
        }
        return;
    }
    int pb = bid - 1;
    if (pb < CAST512) {
        int i = pb * 512 + t;
        float4 v = x4[i];
        ushort4 o;
        o.x = f2bf(v.x); o.y = f2bf(v.y); o.z = f2bf(v.z); o.w = f2bf(v.w);
        XB4[i] = o;
    } else if (pb < CAST512 + 64) {
        int idx = (pb - CAST512) * 512 + t;
        int k = idx >> 7, n = idx & 127;
        float v = (k < 128) ? Ws0[k * 128 + n] : Wn0[(k - 128) * 128 + n];
        BT0[n * 256 + k] = f2bf(v);
    } else if (pb < CAST512 + 128) {
        int idx = (pb - CAST512 - 64) * 512 + t;
        int k = idx >> 7, n = idx & 127;
        float v = (k < 128) ? Ws1[k * 128 + n] : Wn1[(k - 128) * 128 + n];
        BT1[n * 256 + k] = f2bf(v);
    } else {
        int idx = (pb - CAST512 - 128) * 512 + t;
        if (idx < 96 * 128) {
            int n = idx >> 7, k = idx & 127;
            float v = 0.f;
            if (n < 48) { if (n < 47) v = Ws2[k * 47 + n]; }
            else        { int cc = n - 48; if (cc < 47) v = Wn2[k * 47 + cc]; }
            BT2[n * 128 + k] = f2bf(v);
        }
    }
}

__global__ __launch_bounds__(256) void k_scatter(const int* __restrict__ src,
                                                 const int* __restrict__ dst,
                                                 const int* __restrict__ gbase,
                                                 unsigned int* __restrict__ eb) {
    __shared__ int cur[NBK];
    int b = blockIdx.x, t = threadIdx.x;
    for (int i = t; i < NBK; i += 256) cur[i] = gbase[b * NBK + i];
    __syncthreads();
    int beg = b * CHUNK, end = min(beg + CHUNK, NE);
    for (int i = beg + t; i < end; i += 256) {
        int d = dst[i];
        int p = atomicAdd(&cur[d >> 8], 1);
        eb[p] = ((unsigned int)(d & 255) << 24) | (unsigned int)src[i];
    }
}

// fused: per-bucket degree hist -> LDS scan -> row_ptr -> col fill
__global__ __launch_bounds__(256) void k_csr(const unsigned int* __restrict__ eb,
                                             const int* __restrict__ boff,
                                             int* __restrict__ rp,
                                             int* __restrict__ col) {
    __shared__ int h[256];
    __shared__ int sc[256];
    __shared__ int cur[256];
    int b = blockIdx.x, t = threadIdx.x;
    h[t] = 0;
    __syncthreads();
    int beg = boff[b], end = boff[b + 1];
    for (int e = beg + t; e < end; e += 256)
        atomicAdd(&h[eb[e] >> 24], 1);
    __syncthreads();
    int c = h[t];
    sc[t] = c;
    __syncthreads();
    for (int o = 1; o < 256; o <<= 1) {
        int v = (t >= o) ? sc[t - o] : 0;
        __syncthreads();
        sc[t] += v;
        __syncthreads();
    }
    int excl = beg + sc[t] - c;
    int node = (b << 8) + t;
    if (node < NN) rp[node] = excl;
    if (node == NN - 1) rp[NN] = NE;
    cur[t] = excl;
    __syncthreads();
    for (int e = beg + t; e < end; e += 256) {
        unsigned int p = eb[e];
        int pos = atomicAdd(&cur[p >> 24], 1);
        col[pos] = (int)(p & 0xFFFFFFu);
    }
}

// ======== mean-aggregate gather 128-feat: grid-strided, 2 edges/load (R5 form) ========

__global__ __launch_bounds__(256) void k_gather128(
        const uint2* __restrict__ hb2,   // [node][32] uint2 (256B bf16 rows)
        const int* __restrict__ rp, const int* __restrict__ col,
        uint2* __restrict__ hnb2) {
    int wave = blockIdx.x * 4 + (threadIdx.x >> 6);
    int lane = threadIdx.x & 63;
    int half = lane >> 5, l32 = lane & 31;
    int n0 = wave * NPW;
    int n1 = min(n0 + NPW, NN);
    for (int node = n0; node < n1; ++node) {
        int beg = rp[node], end = rp[node + 1];
        float a0 = 0.f, a1 = 0.f, a2 = 0.f, a3 = 0.f;
        float b0 = 0.f, b1 = 0.f, b2 = 0.f, b3 = 0.f;
        int e = beg;
        for (; e + 8 <= end; e += 8) {
            int c0 = col[e + half];
            int c1 = col[e + 2 + half];
            int c2 = col[e + 4 + half];
            int c3 = col[e + 6 + half];
            uint2 v0 = hb2[(size_t)c0 * 32 + l32];
            uint2 v1 = hb2[(size_t)c1 * 32 + l32];
            uint2 v2 = hb2[(size_t)c2 * 32 + l32];
            uint2 v3 = hb2[(size_t)c3 * 32 + l32];
            a0 += lo16(v0.x); a1 += hi16(v0.x); a2 += lo16(v0.y); a3 += hi16(v0.y);
            b0 += lo16(v1.x); b1 += hi16(v1.x); b2 += lo16(v1.y); b3 += hi16(v1.y);
            a0 += lo16(v2.x); a1 += hi16(v2.x); a2 += lo16(v2.y); a3 += hi16(v2.y);
            b0 += lo16(v3.x); b1 += hi16(v3.x); b2 += lo16(v3.y); b3 += hi16(v3.y);
        }
        for (; e < end; e += 2) {
            if (e + half < end) {
                uint2 v = hb2[(size_t)col[e + half] * 32 + l32];
                a0 += lo16(v.x); a1 += hi16(v.x); a2 += lo16(v.y); a3 += hi16(v.y);
            }
        }
        float s0 = a0 + b0, s1 = a1 + b1, s2 = a2 + b2, s3 = a3 + b3;
        s0 += __shfl_xor(s0, 32);
        s1 += __shfl_xor(s1, 32);
        s2 += __shfl_xor(s2, 32);
        s3 += __shfl_xor(s3, 32);
        if (half == 0) {
            float d = (float)(end - beg);
            float inv = (d > 0.f) ? 1.0f / d : 0.0f;
            uint2 o;
            o.x = ((unsigned int)f2bf(s1 * inv) << 16) | (unsigned int)f2bf(s0 * inv);
            o.y = ((unsigned int)f2bf(s3 * inv) << 16) | (unsigned int)f2bf(s2 * inv);
            hnb2[(size_t)node * 32 + l32] = o;
        }
    }
}

// ================= MFMA GEMM: outB = bf16(relu([A0|A1] @ BT^T + b)) =================

__global__ __launch_bounds__(256, 2) void k_mgemm(
        const unsigned short* __restrict__ A0,
        const unsigned short* __restrict__ A1,
        const unsigned short* __restrict__ BT,
        const float* __restrict__ bias,
        unsigned short* __restrict__ outB) {
    int t = threadIdx.x;
    int lane = t & 63, wid = t >> 6;
    int wm = wid >> 1, wn = wid & 1;
    int lr = lane & 15, lg = lane >> 4;
    int row0 = blockIdx.x * 128 + wm * 64;
    int colw = wn * 64;
    f32x4 zero = {0.f, 0.f, 0.f, 0.f};
    f32x4 acc[4][4];
#pragma unroll
    for (int a = 0; a < 4; ++a)
#pragma unroll
        for (int b = 0; b < 4; ++b) acc[a][b] = zero;

#pragma unroll
    for (int p = 0; p < 2; ++p) {
        const unsigned short* A = p ? A1 : A0;
        bf16x8 bReg[4][4];
#pragma unroll
        for (int nf = 0; nf < 4; ++nf)
#pragma unroll
            for (int ks = 0; ks < 4; ++ks)
                bReg[nf][ks] = *(const bf16x8*)&BT[(size_t)(colw + nf * 16 + lr) * 256 + p * 128 + ks * 32 + lg * 8];
#pragma unroll
        for (int mf = 0; mf < 4; ++mf) {
            const unsigned short* Ar = A + (size_t)(row0 + mf * 16 + lr) * 128;
            bf16x8 aReg[4];
#pragma unroll
            for (int ks = 0; ks < 4; ++ks)
                aReg[ks] = *(const bf16x8*)&Ar[ks * 32 + lg * 8];
#pragma unroll
            for (int ks = 0; ks < 4; ++ks)
#pragma unroll
                for (int nf = 0; nf < 4; ++nf)
                    acc[mf][nf] = __builtin_amdgcn_mfma_f32_16x16x32_bf16(
                        aReg[ks], bReg[nf][ks], acc[mf][nf], 0, 0, 0);
        }
    }
    __syncthreads();   // A0 aliases outB (in-place): drain all reads first
#pragma unroll
    for (int nf = 0; nf < 4; ++nf) {
        int cidx = colw + nf * 16 + lr;
        float bb = bias[cidx];
#pragma unroll
        for (int mf = 0; mf < 4; ++mf) {
#pragma unroll
            for (int j = 0; j < 4; ++j) {
                int row = row0 + mf * 16 + lg * 4 + j;
                if (row < NN) {
                    float v = fmaxf(acc[mf][nf][j] + bb, 0.f);
                    outB[(size_t)row * 128 + cidx] = f2bf(v);
                }
            }
        }
    }
}

// ====== layer 2 MFMA: S = h2@Ws2+b2 (fp32), T = h2@Wn2 (bf16), BN=96 ======

__global__ __launch_bounds__(256, 2) void k_mgemm47(
        const unsigned short* __restrict__ A,
        const unsigned short* __restrict__ BT2,
        const float* __restrict__ bias,
        float* __restrict__ S,
        unsigned short* __restrict__ TB) {
    int t = threadIdx.x;
    int lane = t & 63, wid = t >> 6;
    int wm = wid >> 1, wn = wid & 1;
    int lr = lane & 15, lg = lane >> 4;
    int row0 = blockIdx.x * 128 + wm * 64;
    int colw = wn * 48;
    f32x4 zero = {0.f, 0.f, 0.f, 0.f};
    f32x4 acc[4][3];
#pragma unroll
    for (int a = 0; a < 4; ++a)
#pragma unroll
        for (int b = 0; b < 3; ++b) acc[a][b] = zero;

    bf16x8 bReg[3][4];
#pragma unroll
    for (int nf = 0; nf < 3; ++nf)
#pragma unroll
        for (int ks = 0; ks < 4; ++ks)
            bReg[nf][ks] = *(const bf16x8*)&BT2[(size_t)(colw + nf * 16 + lr) * 128 + ks * 32 + lg * 8];
#pragma unroll
    for (int mf = 0; mf < 4; ++mf) {
        const unsigned short* Ar = A + (size_t)(row0 + mf * 16 + lr) * 128;
        bf16x8 aReg[4];
#pragma unroll
        for (int ks = 0; ks < 4; ++ks)
            aReg[ks] = *(const bf16x8*)&Ar[ks * 32 + lg * 8];
#pragma unroll
        for (int ks = 0; ks < 4; ++ks)
#pragma unroll
            for (int nf = 0; nf < 3; ++nf)
                acc[mf][nf] = __builtin_amdgcn_mfma_f32_16x16x32_bf16(
                    aReg[ks], bReg[nf][ks], acc[mf][nf], 0, 0, 0);
    }
#pragma unroll
    for (int nf = 0; nf < 3; ++nf) {
        int cidx = colw + nf * 16 + lr;      // 0..95
#pragma unroll
        for (int mf = 0; mf < 4; ++mf) {
#pragma unroll
            for (int j = 0; j < 4; ++j) {
                int row = row0 + mf * 16 + lg * 4 + j;
                if (row < NN) {
                    float v = acc[mf][nf][j];
                    if (cidx < 47)
                        S[(size_t)row * 48 + cidx] = v + bias[cidx];
                    else if (cidx >= 48)
                        TB[(size_t)row * 48 + (cidx - 48)] = f2bf(v);
                }
            }
        }
    }
}

// ======== layer-2 aggregate: out = S + mean(TB), grid-strided, 2 edges/load (R5 form) ========

__global__ __launch_bounds__(256) void k_gather47(
        const unsigned int* __restrict__ TB32,   // [node][24] uint (96B bf16 rows)
        const float2* __restrict__ S2,           // [node][24] float2
        const int* __restrict__ rp, const int* __restrict__ col,
        float* __restrict__ out) {
    int wave = blockIdx.x * 4 + (threadIdx.x >> 6);
    int lane = threadIdx.x & 63;
    int half = lane >> 5, l32 = lane & 31;
    bool act = l32 < 24;
    int n0 = wave * NPW;
    int n1 = min(n0 + NPW, NN);
    for (int node = n0; node < n1; ++node) {
        int beg = rp[node], end = rp[node + 1];
        float c0a = 0.f, c1a = 0.f, c0b = 0.f, c1b = 0.f;
        int e = beg;
        for (; e + 8 <= end; e += 8) {
            int i0 = col[e + half];
            int i1 = col[e + 2 + half];
            int i2 = col[e + 4 + half];
            int i3 = col[e + 6 + half];
            if (act) {
                unsigned int u0 = TB32[(size_t)i0 * 24 + l32];
                unsigned int u1 = TB32[(size_t)i1 * 24 + l32];
                unsigned int u2 = TB32[(size_t)i2 * 24 + l32];
                unsigned int u3 = TB32[(size_t)i3 * 24 + l32];
                c0a += lo16(u0); c1a += hi16(u0);
                c0b += lo16(u1); c1b += hi16(u1);
                c0a += lo16(u2); c1a += hi16(u2);
                c0b += lo16(u3); c1b += hi16(u3);
            }
        }
        for (; e < end; e += 2) {
            if (act && e + half < end) {
                unsigned int u = TB32[(size_t)col[e + half] * 24 + l32];
                c0a += lo16(u); c1a += hi16(u);
            }
        }
        float s0 = c0a + c0b, s1 = c1a + c1b;
        s0 += __shfl_xor(s0, 32);
        s1 += __shfl_xor(s1, 32);
        if (half == 0 && act) {
            float d = (float)(end - beg);
            float inv = (d > 0.f) ? 1.0f / d : 0.0f;
            float2 sv = S2[(size_t)node * 24 + l32];
            int c = l32 * 2;
            out[(size_t)node * 47 + c] = sv.x + s0 * inv;
            if (c + 1 < 47) out[(size_t)node * 47 + c + 1] = sv.y + s1 * inv;
        }
    }
}

// ================= launcher =================

static inline size_t align_up(size_t x, size_t a) { return (x + a - 1) / a * a; }

extern "C" void kernel_launch(void* const* d_in, const int* in_sizes, int n_in,
                              void* d_out, int out_size, void* d_ws, size_t ws_size,
                              hipStream_t stream) {
    const float* x   = (const float*)d_in[0];
    const int* src   = (const int*)d_in[1];
    const int* dst   = (const int*)d_in[2];
    const float* Ws0 = (const float*)d_in[3];
    const float* Wn0 = (const float*)d_in[4];
    const float* b0  = (const float*)d_in[5];
    const float* Ws1 = (const float*)d_in[6];
    const float* Wn1 = (const float*)d_in[7];
    const float* b1  = (const float*)d_in[8];
    const float* Ws2 = (const float*)d_in[9];
    const float* Wn2 = (const float*)d_in[10];
    const float* b2  = (const float*)d_in[11];
    float* out = (float*)d_out;

    char* ws = (char*)d_ws;
    size_t off = 0;
    auto alloc = [&](size_t bytes) -> void* {
        void* p = ws + off; off = align_up(off + bytes, 256); return p;
    };
    int* row_ptr = (int*)alloc((size_t)(NN + 1) * 4);
    int* boff    = (int*)alloc((size_t)(NBK + 1) * 4);
    int* gbase   = (int*)alloc((size_t)NBLK * NBK * 4);
    int* ghist   = (int*)alloc((size_t)NBLK * NBK * 4);
    int* col     = (int*)alloc((size_t)NE * 4);
    unsigned short* XB  = (unsigned short*)alloc((size_t)MPAD * 128 * 2);
    unsigned short* BT0 = (unsigned short*)alloc(128 * 256 * 2);
    unsigned short* BT1 = (unsigned short*)alloc(128 * 256 * 2);
    unsigned short* BT2 = (unsigned short*)alloc(96 * 128 * 2);
    char* big = (char*)alloc((size_t)NN * 48 * 4 * 2);   // 38.4MB, time-shared
    unsigned int* eb    = (unsigned int*)big;            // CSR build
    unsigned int* HNB   = (unsigned int*)big;            // gathered bf16 rows
    float* S            = (float*)big;
    unsigned short* TB  = (unsigned short*)(big + (size_t)NN * 48 * 4);

    // --- CSR build (no global atomics); prep fused into the scan launch ---
    k_hist<<<NBLK, 256, 0, stream>>>(dst, ghist);
    k_basescan_prep<<<1 + CAST512 + 128 + 24, 512, 0, stream>>>(
        ghist, boff, gbase,
        (const float4*)x, (ushort4*)XB, Ws0, Wn0, BT0, Ws1, Wn1, BT1, Ws2, Wn2, BT2);
    k_scatter<<<NBLK, 256, 0, stream>>>(src, dst, gbase, eb);
    k_csr<<<NBK, 256, 0, stream>>>(eb, boff, row_ptr, col);

    int mgrid = MPAD / 128;

    // --- layer 0 (bf16 in-place over XB) ---
    k_gather128<<<GBLK, 256, 0, stream>>>((const uint2*)XB, row_ptr, col, (uint2*)HNB);
    k_mgemm<<<mgrid, 256, 0, stream>>>(XB, (const unsigned short*)HNB, BT0, b0, XB);
    // --- layer 1 (bf16 in-place over XB) ---
    k_gather128<<<GBLK, 256, 0, stream>>>((const uint2*)XB, row_ptr, col, (uint2*)HNB);
    k_mgemm<<<mgrid, 256, 0, stream>>>(XB, (const unsigned short*)HNB, BT1, b1, XB);
    // --- layer 2 ---
    k_mgemm47<<<mgrid, 256, 0, stream>>>(XB, BT2, b2, S, TB);
    k_gather47<<<GBLK, 256, 0, stream>>>((const unsigned int*)TB, (const float2*)S,
                                         row_ptr, col, out);
}